// Round 1
// baseline (73.861 us; speedup 1.0000x reference)
//
#include <hip/hip_runtime.h>
#include <stdint.h>

#define BB 4
#define HH 128
#define WW 128
#define AA 15
#define GG 32
#define NPOS (BB*HH*WW*AA)          // 983040
#define NCHUNK (NPOS/1024)          // 960
#define NBINS 2048
#define TOPK 100
#define CAP 16384

// workspace layout (bytes)
#define OFF_HIST   0                      // uint32[2048]  -> 8192
#define OFF_CHUNK  8192                   // uint32[960]   -> 3840
#define OFF_CTRL   12032                  // int[8]
#define OFF_NEGIDX 12160                  // int[128]
#define OFF_POSVAL 12672                  // float[128]
#define OFF_POSIDX 13184                  // int[128]
#define OFF_CANDV  16384                  // float[CAP]
#define OFF_CANDI  (16384 + CAP*4)        // int[CAP]
#define OFF_FLAG   (16384 + CAP*8)        // uint8[NPOS]

// ctrl indices
#define C_M        0
#define C_NPOS     1
#define C_THRBIN   2
#define C_CANDCNT  3
#define C_NEGCNT   4

__device__ __forceinline__ float iou_one(float py1, float px1, float py2, float px2,
                                         float area_p,
                                         float gy1, float gx1, float gy2, float gx2) {
    float iy1 = fmaxf(py1, gy1);
    float ix1 = fmaxf(px1, gx1);
    float iy2 = fminf(py2, gy2);
    float ix2 = fminf(px2, gx2);
    float ih = fmaxf(iy2 - iy1, 0.0f);
    float iw = fmaxf(ix2 - ix1, 0.0f);
    float inter = ih * iw;
    float area_g = (gy2 - gy1) * (gx2 - gx1);
    return inter / (area_p + area_g - inter);
}

// Pass 1: histogram of IoU>0.5 values, neg flags, per-chunk neg counts
__global__ __launch_bounds__(1024) void k_pass1(const float4* __restrict__ props,
                                                const float* __restrict__ gt,
                                                uint8_t* __restrict__ ws) {
    __shared__ uint32_t sh_hist[NBINS];
    __shared__ float sh_gt[GG*4];
    __shared__ uint32_t sh_red[16];
    int tid = threadIdx.x;
    for (int i = tid; i < NBINS; i += 1024) sh_hist[i] = 0;
    if (tid < GG*4) sh_gt[tid] = gt[tid];
    __syncthreads();

    int pos = blockIdx.x * 1024 + tid;
    float4 p = props[pos];
    float area_p = (p.z - p.x) * (p.w - p.y);
    float maxIou = -1.0f;
    #pragma unroll 4
    for (int g = 0; g < GG; ++g) {
        float iou = iou_one(p.x, p.y, p.z, p.w, area_p,
                            sh_gt[g*4+0], sh_gt[g*4+1], sh_gt[g*4+2], sh_gt[g*4+3]);
        maxIou = fmaxf(maxIou, iou);
        if (iou > 0.5f) {
            int bin = (int)((iou - 0.5f) * 4096.0f);
            if (bin > NBINS-1) bin = NBINS-1;
            atomicAdd(&sh_hist[bin], 1u);
        }
    }
    uint8_t flag = (maxIou < 0.4f) ? 1 : 0;
    ws[OFF_FLAG + pos] = flag;

    unsigned long long bal = __ballot(flag != 0);
    int lane = tid & 63, wid = tid >> 6;
    if (lane == 0) sh_red[wid] = (uint32_t)__popcll(bal);
    __syncthreads();
    if (tid == 0) {
        uint32_t s = 0;
        for (int k = 0; k < 16; ++k) s += sh_red[k];
        ((uint32_t*)(ws + OFF_CHUNK))[blockIdx.x] = s;
    }
    uint32_t* ghist = (uint32_t*)(ws + OFF_HIST);
    for (int i = tid; i < NBINS; i += 1024) {
        uint32_t v = sh_hist[i];
        if (v) atomicAdd(&ghist[i], v);
    }
}

// Pass 2: threshold bin selection + negCount + fill negIdx[0..99]
__global__ __launch_bounds__(1024) void k_select(uint8_t* __restrict__ ws) {
    __shared__ uint32_t sdata[1024];
    __shared__ int sfind;
    uint32_t* ghist = (uint32_t*)(ws + OFF_HIST);
    uint32_t* gchunk = (uint32_t*)(ws + OFF_CHUNK);
    int* ctrl = (int*)(ws + OFF_CTRL);
    int* negIdx = (int*)(ws + OFF_NEGIDX);
    const uint8_t* flags = ws + OFF_FLAG;
    int tid = threadIdx.x;

    // --- suffix-count over histogram via reversed inclusive scan of pair sums ---
    if (tid == 0) sfind = -1;
    uint32_t h2 = ghist[2*tid] + ghist[2*tid+1];   // pair p=tid covers bins 2p,2p+1
    sdata[1023 - tid] = h2;                        // reversed order
    __syncthreads();
    for (int s = 1; s < 1024; s <<= 1) {
        uint32_t v = (tid >= s) ? sdata[tid - s] : 0;
        __syncthreads();
        sdata[tid] += v;
        __syncthreads();
    }
    uint32_t M = sdata[1023];
    uint32_t scanv = sdata[tid];
    uint32_t prev = (tid > 0) ? sdata[tid-1] : 0;
    if (scanv >= TOPK && prev < TOPK) sfind = tid;  // unique r: min rev-index with cum>=K
    __syncthreads();
    if (tid == 0) {
        ctrl[C_M] = (int)M;
        int npos = (int)M; if (npos > TOPK) npos = TOPK;
        ctrl[C_NPOS] = npos;
        int T = 0;
        if (sfind >= 0) {
            int r = sfind, p = 1023 - r;
            uint32_t cumExcl = (r > 0) ? sdata[r-1] : 0;  // bins strictly above pair p
            uint32_t hHigh = ghist[2*p+1];
            T = (cumExcl + hHigh >= TOPK) ? (2*p+1) : (2*p);
        }
        ctrl[C_THRBIN] = T;
    }
    __syncthreads();

    // --- total negative count ---
    uint32_t c = (tid < NCHUNK) ? gchunk[tid] : 0;
    sdata[tid] = c;
    __syncthreads();
    for (int s = 512; s > 0; s >>= 1) {
        if (tid < s) sdata[tid] += sdata[tid + s];
        __syncthreads();
    }
    if (tid == 0) ctrl[C_NEGCNT] = (int)sdata[0];
    __syncthreads();

    // --- fill negIdx with first 100 flagged positions (ascending index) ---
    int base = 0;
    for (int ch = 0; ch < NCHUNK && base < TOPK; ++ch) {
        int idx = ch * 1024 + tid;
        uint32_t f = flags[idx];
        sdata[tid] = f;
        __syncthreads();
        for (int s = 1; s < 1024; s <<= 1) {
            uint32_t v = (tid >= s) ? sdata[tid - s] : 0;
            __syncthreads();
            sdata[tid] += v;
            __syncthreads();
        }
        int incl = (int)sdata[tid];
        int total = (int)sdata[1023];
        if (f && (base + incl - 1) < TOPK) negIdx[base + incl - 1] = idx;
        __syncthreads();
        base += total;
    }
}

// Pass 3: collect candidates in bins >= T*
__global__ __launch_bounds__(1024) void k_collect(const float4* __restrict__ props,
                                                  const float* __restrict__ gt,
                                                  uint8_t* __restrict__ ws) {
    __shared__ float sh_gt[GG*4];
    int* ctrl = (int*)(ws + OFF_CTRL);
    float* candV = (float*)(ws + OFF_CANDV);
    int* candI = (int*)(ws + OFF_CANDI);
    int tid = threadIdx.x;
    if (tid < GG*4) sh_gt[tid] = gt[tid];
    __syncthreads();
    int T = ctrl[C_THRBIN];

    int pos = blockIdx.x * 1024 + tid;
    float4 p = props[pos];
    float area_p = (p.z - p.x) * (p.w - p.y);
    int bhw = pos / AA;
    int a = pos - bhw * AA;
    #pragma unroll 4
    for (int g = 0; g < GG; ++g) {
        float iou = iou_one(p.x, p.y, p.z, p.w, area_p,
                            sh_gt[g*4+0], sh_gt[g*4+1], sh_gt[g*4+2], sh_gt[g*4+3]);
        if (iou > 0.5f) {
            int bin = (int)((iou - 0.5f) * 4096.0f);
            if (bin > NBINS-1) bin = NBINS-1;
            if (bin >= T) {
                int slot = atomicAdd(&ctrl[C_CANDCNT], 1);
                if (slot < CAP) {
                    candV[slot] = iou;
                    candI[slot] = (bhw * GG + g) * AA + a;
                }
            }
        }
    }
}

// Pass 4: exact rank (desc value, asc index) of candidates; keep ranks < n_pos
__global__ __launch_bounds__(1024) void k_rank(uint8_t* __restrict__ ws) {
    __shared__ float sv[1024];
    __shared__ int si[1024];
    int* ctrl = (int*)(ws + OFF_CTRL);
    float* candV = (float*)(ws + OFF_CANDV);
    int* candI = (int*)(ws + OFF_CANDI);
    float* posV = (float*)(ws + OFF_POSVAL);
    int* posI = (int*)(ws + OFF_POSIDX);
    int C = ctrl[C_CANDCNT]; if (C > CAP) C = CAP;
    int npos = ctrl[C_NPOS];
    int tid = threadIdx.x;

    for (int i0 = 0; i0 < C; i0 += 1024) {
        int i = i0 + tid;
        float vi = (i < C) ? candV[i] : 0.0f;
        int xi = (i < C) ? candI[i] : 0;
        int rank = 0;
        for (int j0 = 0; j0 < C; j0 += 1024) {
            int j = j0 + tid;
            sv[tid] = (j < C) ? candV[j] : -1.0f;
            si[tid] = (j < C) ? candI[j] : 0x7fffffff;
            __syncthreads();
            int lim = min(1024, C - j0);
            if (i < C) {
                for (int jj = 0; jj < lim; ++jj) {
                    float vj = sv[jj]; int xj = si[jj];
                    rank += (vj > vi) || (vj == vi && xj < xi);
                }
            }
            __syncthreads();
        }
        if (i < C && rank < npos) { posV[rank] = vi; posI[rank] = xi; }
    }
}

// Pass 5: write 100x20 output
__global__ __launch_bounds__(128) void k_out(const float* __restrict__ props,
                                             const float* __restrict__ gt,
                                             const float* __restrict__ cls,
                                             const uint8_t* __restrict__ ws,
                                             float* __restrict__ out) {
    int i = threadIdx.x;
    if (i >= TOPK) return;
    const int* ctrl = (const int*)(ws + OFF_CTRL);
    const int* negIdx = (const int*)(ws + OFF_NEGIDX);
    const int* posI = (const int*)(ws + OFF_POSIDX);
    int npos = ctrl[C_NPOS];
    int negCount = ctrl[C_NEGCNT];

    float o[20];
    #pragma unroll
    for (int k = 0; k < 20; ++k) o[k] = 0.0f;

    if (i < npos) {
        int flat = posI[i];
        int a = flat % AA; int t = flat / AA;
        int g = t % GG; t /= GG;
        int w = t % WW; t /= WW;
        int h = t % HH; int b = t / HH;
        int pbase = (((b*HH + h)*WW + w)*AA + a) * 4;
        float y1 = props[pbase+0], x1 = props[pbase+1], y2 = props[pbase+2], x2 = props[pbase+3];
        float gy1 = gt[g*4+0], gx1 = gt[g*4+1], gy2 = gt[g*4+2], gx2 = gt[g*4+3];
        float pcy = (y1 + y2) * 0.5f, pcx = (x1 + x2) * 0.5f, ph = y2 - y1, pw = x2 - x1;
        float gcy = (gy1 + gy2) * 0.5f, gcx = (gx1 + gx2) * 0.5f, gh = gy2 - gy1, gw = gx2 - gx1;
        int cbase = ((b*HH + h)*WW + w) * (2*AA) + 2*a;
        o[0] = pcy; o[1] = pcx; o[2] = ph; o[3] = pw;
        o[4] = cls[cbase]; o[5] = cls[cbase+1];
        o[6] = gcy; o[7] = gcx; o[8] = gh; o[9] = gw;
        o[10] = 1.0f; o[11] = 0.0f;
        if (i < negCount) {
            int nf = negIdx[i];
            int na = nf % AA; int tt = nf / AA;
            int nw = tt % WW; tt /= WW;
            int nh = tt % HH; int nb = tt / HH;
            int nbase = ((nb*HH + nh)*WW + nw) * (2*AA) + 2*na;
            o[12] = cls[nbase]; o[13] = cls[nbase+1];
            o[14] = 0.0f; o[15] = 1.0f;
        }
        o[16] = (gcy - pcy) / ph;
        o[17] = (gcx - pcx) / pw;
        o[18] = (gh - ph) / ph;
        o[19] = (gw - pw) / pw;
    }
    #pragma unroll
    for (int k = 0; k < 20; ++k) out[i*20 + k] = o[k];
}

extern "C" void kernel_launch(void* const* d_in, const int* in_sizes, int n_in,
                              void* d_out, int out_size, void* d_ws, size_t ws_size,
                              hipStream_t stream) {
    (void)in_sizes; (void)n_in; (void)out_size; (void)ws_size;
    const float* props = (const float*)d_in[0];
    // d_in[1] = anchors (unused by the reference forward)
    const float* gt = (const float*)d_in[2];
    const float* cls = (const float*)d_in[3];
    uint8_t* ws = (uint8_t*)d_ws;

    hipMemsetAsync(ws, 0, 16384, stream);  // hist + chunk counts + ctrl + negIdx + pos buffers
    k_pass1<<<NCHUNK, 1024, 0, stream>>>((const float4*)props, gt, ws);
    k_select<<<1, 1024, 0, stream>>>(ws);
    k_collect<<<NCHUNK, 1024, 0, stream>>>((const float4*)props, gt, ws);
    k_rank<<<1, 1024, 0, stream>>>(ws);
    k_out<<<1, 128, 0, stream>>>(props, gt, cls, ws, (float*)d_out);
}

// Round 4
// 73.376 us; speedup vs baseline: 1.0066x; 1.0066x over previous
//
#include <hip/hip_runtime.h>
#include <stdint.h>

#define BB 4
#define HH 128
#define WW 128
#define AA 15
#define GG 32
#define NPOS (BB*HH*WW*AA)          // 983040
#define NCHUNK (NPOS/1024)          // 960
#define NBINS 2048
#define TOPK 100
#define CAP 16384

// workspace layout (bytes)
#define OFF_HIST   0                      // uint32[2048]  -> 8192
#define OFF_CHUNK  8192                   // uint32[960]   -> 3840
#define OFF_CTRL   12032                  // int[8]
#define OFF_NEGIDX 12160                  // int[128]
#define OFF_POSVAL 12672                  // float[128]
#define OFF_POSIDX 13184                  // int[128]
#define OFF_CANDV  16384                  // float[CAP]
#define OFF_CANDI  (16384 + CAP*4)        // int[CAP]
#define OFF_FLAG   (16384 + CAP*8)        // uint8[NPOS]

// ctrl indices
#define C_M        0
#define C_NPOS     1
#define C_THRBIN   2
#define C_CANDCNT  3
#define C_NEGCNT   4

__device__ __forceinline__ float iou_one(float py1, float px1, float py2, float px2,
                                         float area_p,
                                         float gy1, float gx1, float gy2, float gx2) {
    float iy1 = fmaxf(py1, gy1);
    float ix1 = fmaxf(px1, gx1);
    float iy2 = fminf(py2, gy2);
    float ix2 = fminf(px2, gx2);
    float ih = fmaxf(iy2 - iy1, 0.0f);
    float iw = fmaxf(ix2 - ix1, 0.0f);
    float inter = ih * iw;
    float area_g = (gy2 - gy1) * (gx2 - gx1);
    return inter / (area_p + area_g - inter);
}

// Pass 0: zero the histogram + ctrl (replaces the 40us hipMemsetAsync fill)
__global__ __launch_bounds__(1024) void k_zero(uint8_t* __restrict__ ws) {
    int tid = threadIdx.x;
    uint32_t* ghist = (uint32_t*)(ws + OFF_HIST);
    ghist[tid] = 0u;
    ghist[tid + 1024] = 0u;
    if (tid < 8) ((int*)(ws + OFF_CTRL))[tid] = 0;
}

// Pass 1: histogram of IoU>0.5 values, neg flags, per-chunk neg counts
__global__ __launch_bounds__(1024) void k_pass1(const float4* __restrict__ props,
                                                const float* __restrict__ gt,
                                                uint8_t* __restrict__ ws) {
    __shared__ uint32_t sh_hist[NBINS];
    __shared__ float sh_gt[GG*4];
    __shared__ uint32_t sh_red[16];
    int tid = threadIdx.x;
    for (int i = tid; i < NBINS; i += 1024) sh_hist[i] = 0;
    if (tid < GG*4) sh_gt[tid] = gt[tid];
    __syncthreads();

    int pos = blockIdx.x * 1024 + tid;
    float4 p = props[pos];
    float area_p = (p.z - p.x) * (p.w - p.y);
    float maxIou = -1.0f;
    #pragma unroll 4
    for (int g = 0; g < GG; ++g) {
        float iou = iou_one(p.x, p.y, p.z, p.w, area_p,
                            sh_gt[g*4+0], sh_gt[g*4+1], sh_gt[g*4+2], sh_gt[g*4+3]);
        maxIou = fmaxf(maxIou, iou);
        if (iou > 0.5f) {
            int bin = (int)((iou - 0.5f) * 4096.0f);
            if (bin > NBINS-1) bin = NBINS-1;
            atomicAdd(&sh_hist[bin], 1u);
        }
    }
    uint8_t flag = (maxIou < 0.4f) ? 1 : 0;
    ws[OFF_FLAG + pos] = flag;

    unsigned long long bal = __ballot(flag != 0);
    int lane = tid & 63, wid = tid >> 6;
    if (lane == 0) sh_red[wid] = (uint32_t)__popcll(bal);
    __syncthreads();
    if (tid == 0) {
        uint32_t s = 0;
        for (int k = 0; k < 16; ++k) s += sh_red[k];
        ((uint32_t*)(ws + OFF_CHUNK))[blockIdx.x] = s;
    }
    uint32_t* ghist = (uint32_t*)(ws + OFF_HIST);
    for (int i = tid; i < NBINS; i += 1024) {
        uint32_t v = sh_hist[i];
        if (v) atomicAdd(&ghist[i], v);
    }
}

// Pass 2: threshold bin selection + negCount + fill negIdx[0..99]
__global__ __launch_bounds__(1024) void k_select(uint8_t* __restrict__ ws) {
    __shared__ uint32_t sdata[1024];
    __shared__ int sfind;
    uint32_t* ghist = (uint32_t*)(ws + OFF_HIST);
    uint32_t* gchunk = (uint32_t*)(ws + OFF_CHUNK);
    int* ctrl = (int*)(ws + OFF_CTRL);
    int* negIdx = (int*)(ws + OFF_NEGIDX);
    const uint8_t* flags = ws + OFF_FLAG;
    int tid = threadIdx.x;

    // --- suffix-count over histogram via reversed inclusive scan of pair sums ---
    if (tid == 0) sfind = -1;
    uint32_t h2 = ghist[2*tid] + ghist[2*tid+1];   // pair p=tid covers bins 2p,2p+1
    sdata[1023 - tid] = h2;                        // reversed order
    __syncthreads();
    for (int s = 1; s < 1024; s <<= 1) {
        uint32_t v = (tid >= s) ? sdata[tid - s] : 0;
        __syncthreads();
        sdata[tid] += v;
        __syncthreads();
    }
    uint32_t M = sdata[1023];
    uint32_t scanv = sdata[tid];
    uint32_t prev = (tid > 0) ? sdata[tid-1] : 0;
    if (scanv >= TOPK && prev < TOPK) sfind = tid;  // unique r: min rev-index with cum>=K
    __syncthreads();
    if (tid == 0) {
        ctrl[C_M] = (int)M;
        int npos = (int)M; if (npos > TOPK) npos = TOPK;
        ctrl[C_NPOS] = npos;
        int T = 0;
        if (sfind >= 0) {
            int r = sfind, p = 1023 - r;
            uint32_t cumExcl = (r > 0) ? sdata[r-1] : 0;  // bins strictly above pair p
            uint32_t hHigh = ghist[2*p+1];
            T = (cumExcl + hHigh >= TOPK) ? (2*p+1) : (2*p);
        }
        ctrl[C_THRBIN] = T;
        ctrl[C_CANDCNT] = 0;   // re-zero for k_collect (redundant with k_zero, harmless)
    }
    __syncthreads();

    // --- total negative count ---
    uint32_t c = (tid < NCHUNK) ? gchunk[tid] : 0;
    sdata[tid] = c;
    __syncthreads();
    for (int s = 512; s > 0; s >>= 1) {
        if (tid < s) sdata[tid] += sdata[tid + s];
        __syncthreads();
    }
    if (tid == 0) ctrl[C_NEGCNT] = (int)sdata[0];
    __syncthreads();

    // --- fill negIdx with first 100 flagged positions (ascending index) ---
    int base = 0;
    for (int ch = 0; ch < NCHUNK && base < TOPK; ++ch) {
        int idx = ch * 1024 + tid;
        uint32_t f = flags[idx];
        sdata[tid] = f;
        __syncthreads();
        for (int s = 1; s < 1024; s <<= 1) {
            uint32_t v = (tid >= s) ? sdata[tid - s] : 0;
            __syncthreads();
            sdata[tid] += v;
            __syncthreads();
        }
        int incl = (int)sdata[tid];
        int total = (int)sdata[1023];
        if (f && (base + incl - 1) < TOPK) negIdx[base + incl - 1] = idx;
        __syncthreads();
        base += total;
    }
}

// Pass 3: collect candidates in bins >= T*
__global__ __launch_bounds__(1024) void k_collect(const float4* __restrict__ props,
                                                  const float* __restrict__ gt,
                                                  uint8_t* __restrict__ ws) {
    __shared__ float sh_gt[GG*4];
    int* ctrl = (int*)(ws + OFF_CTRL);
    float* candV = (float*)(ws + OFF_CANDV);
    int* candI = (int*)(ws + OFF_CANDI);
    int tid = threadIdx.x;
    if (tid < GG*4) sh_gt[tid] = gt[tid];
    __syncthreads();
    int T = ctrl[C_THRBIN];

    int pos = blockIdx.x * 1024 + tid;
    float4 p = props[pos];
    float area_p = (p.z - p.x) * (p.w - p.y);
    int bhw = pos / AA;
    int a = pos - bhw * AA;
    #pragma unroll 4
    for (int g = 0; g < GG; ++g) {
        float iou = iou_one(p.x, p.y, p.z, p.w, area_p,
                            sh_gt[g*4+0], sh_gt[g*4+1], sh_gt[g*4+2], sh_gt[g*4+3]);
        if (iou > 0.5f) {
            int bin = (int)((iou - 0.5f) * 4096.0f);
            if (bin > NBINS-1) bin = NBINS-1;
            if (bin >= T) {
                int slot = atomicAdd(&ctrl[C_CANDCNT], 1);
                if (slot < CAP) {
                    candV[slot] = iou;
                    candI[slot] = (bhw * GG + g) * AA + a;
                }
            }
        }
    }
}

// Pass 4+5 merged: exact rank (desc value, asc index) then write 100x20 output.
__global__ __launch_bounds__(1024) void k_rankout(const float* __restrict__ props,
                                                  const float* __restrict__ gt,
                                                  const float* __restrict__ cls,
                                                  uint8_t* __restrict__ ws,
                                                  float* __restrict__ out) {
    __shared__ float sv[1024];
    __shared__ int si[1024];
    int* ctrl = (int*)(ws + OFF_CTRL);
    float* candV = (float*)(ws + OFF_CANDV);
    int* candI = (int*)(ws + OFF_CANDI);
    float* posV = (float*)(ws + OFF_POSVAL);
    int* posI = (int*)(ws + OFF_POSIDX);
    int C = ctrl[C_CANDCNT]; if (C > CAP) C = CAP;
    int npos = ctrl[C_NPOS];
    int tid = threadIdx.x;

    // ---- rank phase (verbatim round-1 k_rank) ----
    for (int i0 = 0; i0 < C; i0 += 1024) {
        int i = i0 + tid;
        float vi = (i < C) ? candV[i] : 0.0f;
        int xi = (i < C) ? candI[i] : 0;
        int rank = 0;
        for (int j0 = 0; j0 < C; j0 += 1024) {
            int j = j0 + tid;
            sv[tid] = (j < C) ? candV[j] : -1.0f;
            si[tid] = (j < C) ? candI[j] : 0x7fffffff;
            __syncthreads();
            int lim = min(1024, C - j0);
            if (i < C) {
                for (int jj = 0; jj < lim; ++jj) {
                    float vj = sv[jj]; int xj = si[jj];
                    rank += (vj > vi) || (vj == vi && xj < xi);
                }
            }
            __syncthreads();
        }
        if (i < C && rank < npos) { posV[rank] = vi; posI[rank] = xi; }
    }
    __syncthreads();

    // ---- output phase (verbatim round-1 k_out, i = tid) ----
    int i = tid;
    if (i >= TOPK) return;
    const int* negIdx = (const int*)(ws + OFF_NEGIDX);
    int negCount = ctrl[C_NEGCNT];

    float o[20];
    #pragma unroll
    for (int k = 0; k < 20; ++k) o[k] = 0.0f;

    if (i < npos) {
        int flat = posI[i];
        int a = flat % AA; int t = flat / AA;
        int g = t % GG; t /= GG;
        int w = t % WW; t /= WW;
        int h = t % HH; int b = t / HH;
        int pbase = (((b*HH + h)*WW + w)*AA + a) * 4;
        float y1 = props[pbase+0], x1 = props[pbase+1], y2 = props[pbase+2], x2 = props[pbase+3];
        float gy1 = gt[g*4+0], gx1 = gt[g*4+1], gy2 = gt[g*4+2], gx2 = gt[g*4+3];
        float pcy = (y1 + y2) * 0.5f, pcx = (x1 + x2) * 0.5f, ph = y2 - y1, pw = x2 - x1;
        float gcy = (gy1 + gy2) * 0.5f, gcx = (gx1 + gx2) * 0.5f, gh = gy2 - gy1, gw = gx2 - gx1;
        int cbase = ((b*HH + h)*WW + w) * (2*AA) + 2*a;
        o[0] = pcy; o[1] = pcx; o[2] = ph; o[3] = pw;
        o[4] = cls[cbase]; o[5] = cls[cbase+1];
        o[6] = gcy; o[7] = gcx; o[8] = gh; o[9] = gw;
        o[10] = 1.0f; o[11] = 0.0f;
        if (i < negCount) {
            int nf = negIdx[i];
            int na = nf % AA; int tt = nf / AA;
            int nw = tt % WW; tt /= WW;
            int nh = tt % HH; int nb = tt / HH;
            int nbase = ((nb*HH + nh)*WW + nw) * (2*AA) + 2*na;
            o[12] = cls[nbase]; o[13] = cls[nbase+1];
            o[14] = 0.0f; o[15] = 1.0f;
        }
        o[16] = (gcy - pcy) / ph;
        o[17] = (gcx - pcx) / pw;
        o[18] = (gh - ph) / ph;
        o[19] = (gw - pw) / pw;
    }
    #pragma unroll
    for (int k = 0; k < 20; ++k) out[i*20 + k] = o[k];
}

extern "C" void kernel_launch(void* const* d_in, const int* in_sizes, int n_in,
                              void* d_out, int out_size, void* d_ws, size_t ws_size,
                              hipStream_t stream) {
    (void)in_sizes; (void)n_in; (void)out_size; (void)ws_size;
    const float* props = (const float*)d_in[0];
    // d_in[1] = anchors (unused by the reference forward)
    const float* gt = (const float*)d_in[2];
    const float* cls = (const float*)d_in[3];
    uint8_t* ws = (uint8_t*)d_ws;

    k_zero<<<1, 1024, 0, stream>>>(ws);
    k_pass1<<<NCHUNK, 1024, 0, stream>>>((const float4*)props, gt, ws);
    k_select<<<1, 1024, 0, stream>>>(ws);
    k_collect<<<NCHUNK, 1024, 0, stream>>>((const float4*)props, gt, ws);
    k_rankout<<<1, 1024, 0, stream>>>(props, gt, cls, ws, (float*)d_out);
}

// Round 5
// 46.123 us; speedup vs baseline: 1.6014x; 1.5909x over previous
//
#include <hip/hip_runtime.h>
#include <stdint.h>

#define BB 4
#define HH 128
#define WW 128
#define AA 15
#define GG 32
#define NPOS (BB*HH*WW*AA)       // 983040
#define NBLK1 240                // k_main blocks (1 per CU, 4096 pos each)
#define POSB 4096
#define NCHUNK (NPOS/1024)       // 960
#define NB 256                   // fine bins over (0.5, 1.0]
#define NBKT 16                  // coarse buckets = NB/16
#define SLOTB 2048               // slots per (block,bucket)
#define TOPK 100
#define CCAP 2048

// workspace layout (bytes); everything read by k_finish is written
// unconditionally by k_main each call -> no zero-init anywhere.
#define OFF_CHUNK 0              // uint32[960]
#define OFF_FLAG  4096           // uint8[NPOS]
#define OFF_HISTB 987136         // uint32[240*256]
#define OFF_BCNT  1232896        // uint32[240*16]
#define OFF_CAND  1248256        // uint2[240*16*2048]  (~63 MB)

__device__ __forceinline__ int fine_bin(float v) {
    // identical instruction in both kernels => bit-identical binning
    int b = (int)__builtin_fmaf(v, 512.0f, -256.0f);
    b = b < 0 ? 0 : (b > NB-1 ? NB-1 : b);
    return b;
}

// Single data pass: per-block uncapped hist, bucketed candidates, neg flags.
__global__ __launch_bounds__(1024) void k_main(const float4* __restrict__ props,
                                               const float* __restrict__ gt,
                                               uint8_t* __restrict__ ws) {
    __shared__ float s_gt[GG*4];
    __shared__ uint32_t s_hist[NB];
    __shared__ uint32_t s_bcnt[NBKT];
    __shared__ uint32_t s_red[64];
    int tid = threadIdx.x;
    if (tid < GG*4) s_gt[tid] = gt[tid];
    if (tid < NB) s_hist[tid] = 0u;
    if (tid < NBKT) s_bcnt[tid] = 0u;
    __syncthreads();

    uint2* candB = (uint2*)(ws + OFF_CAND) + (size_t)blockIdx.x * NBKT * SLOTB;

    for (int k = 0; k < 4; ++k) {
        int pos = blockIdx.x * POSB + k*1024 + tid;
        float4 p = props[pos];                      // (y1,x1,y2,x2)
        float area_p = (p.z - p.x) * (p.w - p.y);
        int bhw = pos / AA;
        int a = pos - bhw * AA;
        bool neg = true;
        #pragma unroll
        for (int g = 0; g < GG; ++g) {
            float gy1 = s_gt[g*4+0], gx1 = s_gt[g*4+1];
            float gy2 = s_gt[g*4+2], gx2 = s_gt[g*4+3];
            float ih = fmaxf(fminf(p.z, gy2) - fmaxf(p.x, gy1), 0.0f);
            float iw = fmaxf(fminf(p.w, gx2) - fmaxf(p.y, gx1), 0.0f);
            float inter = ih * iw;
            float area_g = (gy2 - gy1) * (gx2 - gx1);
            float u = area_p + area_g - inter;      // reference op order
            // conservative screen: failing pairs have exact iou <= 0.3900001,
            // safely below both 0.4 and 0.5 thresholds.
            if (inter > 0.39f * u) {
                float v = inter / u;                // exact reference value
                neg = neg && (v < 0.4f);
                if (v > 0.5f) {
                    int bin = fine_bin(v);
                    atomicAdd(&s_hist[bin], 1u);    // UNCAPPED count (r2/r3 lesson)
                    int bkt = bin >> 4;
                    uint32_t slot = atomicAdd(&s_bcnt[bkt], 1u);
                    if (slot < SLOTB)
                        candB[bkt*SLOTB + slot] =
                            make_uint2(__float_as_uint(v),
                                       (uint32_t)((bhw*GG + g)*AA + a));
                }
            }
        }
        ws[OFF_FLAG + pos] = neg ? 1 : 0;
        unsigned long long bal = __ballot(neg);
        if ((tid & 63) == 0) s_red[k*16 + (tid >> 6)] = (uint32_t)__popcll(bal);
    }
    __syncthreads();
    if (tid < 4) {
        uint32_t s = 0;
        #pragma unroll
        for (int w = 0; w < 16; ++w) s += s_red[tid*16 + w];
        ((uint32_t*)(ws + OFF_CHUNK))[blockIdx.x*4 + tid] = s;
    }
    if (tid < NB) ((uint32_t*)(ws + OFF_HISTB))[blockIdx.x*NB + tid] = s_hist[tid];
    if (tid < NBKT) {
        uint32_t c = s_bcnt[tid]; if (c > SLOTB) c = SLOTB;
        ((uint32_t*)(ws + OFF_BCNT))[blockIdx.x*NBKT + tid] = c;
    }
}

__device__ __forceinline__ uint32_t incl_scan(uint32_t* s, int tid, uint32_t v) {
    s[tid] = v; __syncthreads();
    for (int st = 1; st < 1024; st <<= 1) {
        uint32_t t = (tid >= st) ? s[tid - st] : 0u;
        __syncthreads();
        s[tid] += t;
        __syncthreads();
    }
    return s[tid];
}

// Single block: hist-sum -> T/npos, gather+rank positives, negatives, output.
__global__ __launch_bounds__(1024) void k_finish(const float* __restrict__ props,
                                                 const float* __restrict__ gt,
                                                 const float* __restrict__ cls,
                                                 uint8_t* __restrict__ ws,
                                                 float* __restrict__ out) {
    __shared__ uint32_t sdata[1024];
    __shared__ uint32_t s_tot[NB];
    __shared__ float sc_v[CCAP];
    __shared__ int   sc_i[CCAP];
    __shared__ int s_posI[128];
    __shared__ int s_negI[128];
    __shared__ float s_gt[GG*4];
    __shared__ int s_T, s_M, s_c2, s_negTot;

    int tid = threadIdx.x;
    if (tid < GG*4) s_gt[tid] = gt[tid];
    if (tid == 0) { s_T = 0; s_c2 = 0; }

    // --- 1. total histogram: 4 partial sums of 60 blocks each ---
    {
        const uint32_t* histB = (const uint32_t*)(ws + OFF_HISTB);
        int part = tid >> 8;          // 0..3
        int t = tid & 255;
        uint32_t ssum = 0;
        for (int blk = part*60; blk < part*60 + 60; ++blk) ssum += histB[blk*NB + t];
        sdata[tid] = ssum;
        __syncthreads();
        if (tid < NB) s_tot[tid] = sdata[tid] + sdata[tid+256] + sdata[tid+512] + sdata[tid+768];
        __syncthreads();
    }

    // --- 2. suffix counts -> M, T ---
    if (tid < NB) sdata[tid] = s_tot[NB-1 - tid];     // reversed
    __syncthreads();
    for (int st = 1; st < NB; st <<= 1) {
        uint32_t v = (tid >= st && tid < NB) ? sdata[tid - st] : 0u;
        __syncthreads();
        if (tid < NB) sdata[tid] += v;
        __syncthreads();
    }
    // sdata[r] = count(bin >= NB-1-r); count_ge(b) = sdata[NB-1-b]
    if (tid == 0) s_M = (int)sdata[NB-1];
    if (tid < NB) {
        uint32_t M  = sdata[NB-1];
        uint32_t ge  = sdata[NB-1 - tid];
        uint32_t geN = (tid < NB-1) ? sdata[NB-2 - tid] : 0u;
        if (M >= TOPK && ge >= TOPK && geN < TOPK) s_T = tid;   // unique
    }
    __syncthreads();
    int T = s_T;
    int M = s_M;
    int npos = M < TOPK ? M : TOPK;

    // --- 3. gather candidates with bin >= T from buckets >= T>>4 ---
    {
        const uint32_t* gbcnt = (const uint32_t*)(ws + OFF_BCNT);
        const uint2* cand0 = (const uint2*)(ws + OFF_CAND);
        int cT = T >> 4;
        int W = NBKT - cT;
        for (int pIdx = tid; pIdx < NBLK1 * W; pIdx += 1024) {
            int blk = pIdx / W;
            int bkt = cT + (pIdx - blk * W);
            uint32_t cnt = gbcnt[blk*NBKT + bkt];
            const uint2* cb = cand0 + ((size_t)blk*NBKT + bkt) * SLOTB;
            for (uint32_t j = 0; j < cnt; ++j) {
                uint2 e = cb[j];
                float v = __uint_as_float(e.x);
                if (fine_bin(v) >= T) {
                    int slot = atomicAdd(&s_c2, 1);
                    if (slot < CCAP) { sc_v[slot] = v; sc_i[slot] = (int)e.y; }
                }
            }
        }
        __syncthreads();
    }

    // --- 4. exact rank (desc value, asc flat index = jax tie-break) ---
    {
        int C2 = s_c2; if (C2 > CCAP) C2 = CCAP;
        for (int e = tid; e < C2; e += 1024) {
            float vi = sc_v[e]; int xi = sc_i[e];
            int rank = 0;
            for (int j = 0; j < C2; ++j) {
                float vj = sc_v[j]; int xj = sc_i[j];
                rank += (vj > vi) || (vj == vi && xj < xi);
            }
            if (rank < npos) s_posI[rank] = xi;
        }
        __syncthreads();
    }

    // --- 5. total negatives (chunk-count reduce, r4-verified) ---
    {
        const uint32_t* gchunk = (const uint32_t*)(ws + OFF_CHUNK);
        sdata[tid] = (tid < NCHUNK) ? gchunk[tid] : 0u;
        __syncthreads();
        for (int st = 512; st > 0; st >>= 1) {
            if (tid < st) sdata[tid] += sdata[tid + st];
            __syncthreads();
        }
        if (tid == 0) s_negTot = (int)sdata[0];
        __syncthreads();
    }

    // --- 6. first TOPK neg positions (r4-verified chunked scan) ---
    {
        const uint8_t* flags = ws + OFF_FLAG;
        int base = 0;
        for (int ch = 0; ch < NCHUNK && base < TOPK; ++ch) {
            int idx = ch*1024 + tid;
            uint32_t f = flags[idx];
            uint32_t ic = incl_scan(sdata, tid, f);
            int total = (int)sdata[1023];
            if (f && (base + (int)ic - 1) < TOPK) s_negI[base + ic - 1] = idx;
            __syncthreads();
            base += total;
        }
        __syncthreads();
    }

    // --- 7. write 100 x 20 output ---
    int i = tid;
    if (i >= TOPK) return;
    int negCount = s_negTot;
    float o[20];
    #pragma unroll
    for (int k = 0; k < 20; ++k) o[k] = 0.0f;

    if (i < npos) {
        int flat = s_posI[i];
        int a = flat % AA; int t = flat / AA;
        int g = t % GG; int bhw = t / GG;
        int pbase = (bhw * AA + a) * 4;
        float y1 = props[pbase+0], x1 = props[pbase+1];
        float y2 = props[pbase+2], x2 = props[pbase+3];
        float gy1 = s_gt[g*4+0], gx1 = s_gt[g*4+1];
        float gy2 = s_gt[g*4+2], gx2 = s_gt[g*4+3];
        float pcy = (y1 + y2) * 0.5f, pcx = (x1 + x2) * 0.5f;
        float ph = y2 - y1, pw = x2 - x1;
        float gcy = (gy1 + gy2) * 0.5f, gcx = (gx1 + gx2) * 0.5f;
        float gh = gy2 - gy1, gw = gx2 - gx1;
        int cbase = bhw * (2*AA) + 2*a;
        o[0] = pcy; o[1] = pcx; o[2] = ph; o[3] = pw;
        o[4] = cls[cbase]; o[5] = cls[cbase+1];
        o[6] = gcy; o[7] = gcx; o[8] = gh; o[9] = gw;
        o[10] = 1.0f; o[11] = 0.0f;
        if (i < negCount) {
            int nf = s_negI[i];
            int na = nf % AA; int nbhw = nf / AA;
            int nbase = nbhw * (2*AA) + 2*na;
            o[12] = cls[nbase]; o[13] = cls[nbase+1];
            o[14] = 0.0f; o[15] = 1.0f;
        }
        o[16] = (gcy - pcy) / ph;
        o[17] = (gcx - pcx) / pw;
        o[18] = (gh - ph) / ph;
        o[19] = (gw - pw) / pw;
    }
    #pragma unroll
    for (int k = 0; k < 20; ++k) out[i*20 + k] = o[k];
}

extern "C" void kernel_launch(void* const* d_in, const int* in_sizes, int n_in,
                              void* d_out, int out_size, void* d_ws, size_t ws_size,
                              hipStream_t stream) {
    (void)in_sizes; (void)n_in; (void)out_size; (void)ws_size;
    const float* props = (const float*)d_in[0];
    // d_in[1] = anchors (unused by the reference forward)
    const float* gt = (const float*)d_in[2];
    const float* cls = (const float*)d_in[3];
    uint8_t* ws = (uint8_t*)d_ws;

    k_main<<<NBLK1, 1024, 0, stream>>>((const float4*)props, gt, ws);
    k_finish<<<1, 1024, 0, stream>>>(props, gt, cls, ws, (float*)d_out);
}